// Round 2
// baseline (587.750 us; speedup 1.0000x reference)
//
#include <hip/hip_runtime.h>

#define N_TOK   8192
#define TOPK    2
#define N_EXP   8
#define DM      1024
#define DFF     2048
#define CAP     3072

typedef __attribute__((ext_vector_type(8))) short bf16x8;
typedef __attribute__((ext_vector_type(4))) float f32x4;

__device__ __forceinline__ unsigned short f2bf(float x) {
    union { float f; unsigned u; } un; un.f = x;
    unsigned r = un.u + 0x7fffu + ((un.u >> 16) & 1u);
    return (unsigned short)(r >> 16);
}
__device__ __forceinline__ float bf2f(unsigned short u) {
    union { unsigned u; float f; } c; c.u = ((unsigned)u) << 16; return c.f;
}

__device__ __forceinline__ void glds16(const void* g, void* l) {
    __builtin_amdgcn_global_load_lds(
        (const __attribute__((address_space(1))) unsigned int*)g,
        (__attribute__((address_space(3))) unsigned int*)l, 16, 0, 0);
}

// ---- x fp32 -> bf16 ----
__global__ void cvt_x_kernel(const float4* __restrict__ x, ushort4* __restrict__ xb) {
    int i = blockIdx.x * 256 + threadIdx.x;
    float4 v = x[i];
    ushort4 o;
    o.x = f2bf(v.x); o.y = f2bf(v.y); o.z = f2bf(v.z); o.w = f2bf(v.w);
    xb[i] = o;
}

// ---- transpose + convert, 64x64 tiles: in [E][R][C] fp32 -> out [E][C][R] bf16 ----
__global__ void transpose_cvt64_kernel(const float* __restrict__ inA, const float* __restrict__ inB,
                                       unsigned short* __restrict__ outA, unsigned short* __restrict__ outB,
                                       int R, int C) {
    __shared__ unsigned short L[64][72];
    const int z = blockIdx.z;
    const float* in = (z & 8) ? inB : inA;
    unsigned short* out = (z & 8) ? outB : outA;
    const int e = z & 7;
    const int r0 = blockIdx.y * 64, c0 = blockIdx.x * 64;
    const int t = threadIdx.x;
    const int rr = t >> 4;
    const int cv = t & 15;
    const float4* src = (const float4*)(in + ((size_t)e * R + r0) * C + c0);
    const int c4 = C >> 2;
#pragma unroll
    for (int i = 0; i < 4; i++) {
        int r = rr + 16 * i;
        float4 v = src[(size_t)r * c4 + cv];
        L[r][cv * 4 + 0] = f2bf(v.x);
        L[r][cv * 4 + 1] = f2bf(v.y);
        L[r][cv * 4 + 2] = f2bf(v.z);
        L[r][cv * 4 + 3] = f2bf(v.w);
    }
    __syncthreads();
    unsigned short* dst = out + ((size_t)e * C + c0) * R + r0;
    const int cc = t >> 4;
    const int rv = t & 15;
#pragma unroll
    for (int i = 0; i < 4; i++) {
        int c = cc + 16 * i;
        ushort4 o;
        o.x = L[rv * 4 + 0][c];
        o.y = L[rv * 4 + 1][c];
        o.z = L[rv * 4 + 2][c];
        o.w = L[rv * 4 + 3][c];
        *(ushort4*)(dst + (size_t)c * R + rv * 4) = o;
    }
}

// ---- dispatch: slot assignment per (token, k); also records inverse map ----
__global__ void dispatch_kernel(const int* __restrict__ eidx, const float* __restrict__ ewt,
                                int* __restrict__ counts, int* __restrict__ row_token,
                                float* __restrict__ row_weight, int* __restrict__ slot_of) {
    int i = blockIdx.x * 256 + threadIdx.x;
    if (i < N_TOK * TOPK) {
        int e = eidx[i];
        int pos = atomicAdd(&counts[e], 1);
        int slot = -1;
        if (pos < CAP) {
            slot = e * CAP + pos;
            row_token[slot] = i >> 1;   // TOPK == 2
            row_weight[slot] = ewt[i];
        }
        slot_of[i] = slot;
    }
}

// ===================================================================================
// GEMM1 — 256x(128+128) tile, BK=64, 8 waves, double-buffered 128KB LDS,
// 4-phase counted-vmcnt schedule (T3+T4+T5 per learn_hip m218/m201).
// Phase p: {ds_read subtile ; issue glds16 prefetch ; [vmcnt(N)] ; s_barrier ;
//           setprio(1) 16xMFMA setprio(0) ; s_barrier}
// vmcnt never drains to 0 in the main loop: vmcnt(4)@ph0 (waits prior tile's B2),
// vmcnt(2)@ph3 (waits next tile's A+B1, leaves B2 in flight).
// LDS swizzle: chunk ^= (row&7) (G4 recipe), applied on the pre-swizzled GLOBAL
// source (glds16 writes linearly) and on the ds_read address (rule #21).
// ===================================================================================

#define G1_RD_A(bc, mh) \
    _Pragma("unroll") \
    for (int _mf = 0; _mf < 4; _mf++) { \
        const char* _b = (bc) + aRow + ((mh) * 64 + _mf * 16) * 128; \
        aF[_mf][0] = *(const bf16x8*)(_b + cof0); \
        aF[_mf][1] = *(const bf16x8*)(_b + cof1); \
    }

#define G1_RD_B(bc, region, BF) \
    _Pragma("unroll") \
    for (int _ff = 0; _ff < 2; _ff++) { \
        const char* _b = (bc) + (region) + bRow + _ff * 2048; \
        BF[_ff][0] = *(const bf16x8*)(_b + cof0); \
        BF[_ff][1] = *(const bf16x8*)(_b + cof1); \
    }

#define G1_MM(ACC, mh, BF) \
    _Pragma("unroll") \
    for (int _mf = 0; _mf < 4; _mf++) \
    _Pragma("unroll") \
    for (int _ff = 0; _ff < 2; _ff++) { \
        ACC[(mh) * 4 + _mf][_ff] = __builtin_amdgcn_mfma_f32_16x16x32_bf16(aF[_mf][0], BF[_ff][0], ACC[(mh) * 4 + _mf][_ff], 0, 0, 0); \
        ACC[(mh) * 4 + _mf][_ff] = __builtin_amdgcn_mfma_f32_16x16x32_bf16(aF[_mf][1], BF[_ff][1], ACC[(mh) * 4 + _mf][_ff], 0, 0, 0); \
    }

#define G1_ST_A(bs) \
    _Pragma("unroll") \
    for (int _i = 0; _i < 4; _i++) glds16(xbc + offA[_i], (bs) + _i * 8192);

#define G1_ST_B1(bs) \
    _Pragma("unroll") \
    for (int _j = 0; _j < 2; _j++) glds16(w1c + offB[_j], (bs) + 32768 + _j * 8192);

#define G1_ST_B2(bs) \
    _Pragma("unroll") \
    for (int _j = 0; _j < 2; _j++) glds16(w2c + offB[_j], (bs) + 49152 + _j * 8192);

#define G1_BAR() do { __builtin_amdgcn_s_barrier(); asm volatile("" ::: "memory"); } while (0)

#define G1_ITER(pc, ps) do { \
    const char* bc = smem + (pc) * 65536; \
    char* bs = ldsT + (ps) * 65536; \
    /* phase 0: G, mh=0 */ \
    G1_RD_A(bc, 0); \
    G1_RD_B(bc, 32768, b1F); \
    G1_ST_A(bs); \
    asm volatile("s_waitcnt vmcnt(4)" ::: "memory"); \
    G1_BAR(); \
    __builtin_amdgcn_s_setprio(1); G1_MM(accG, 0, b1F); __builtin_amdgcn_s_setprio(0); \
    G1_BAR(); \
    /* phase 1: V, mh=0 */ \
    G1_RD_B(bc, 49152, b2F); \
    G1_ST_B1(bs); \
    G1_BAR(); \
    __builtin_amdgcn_s_setprio(1); G1_MM(accV, 0, b2F); __builtin_amdgcn_s_setprio(0); \
    G1_BAR(); \
    /* phase 2: G, mh=1 */ \
    G1_RD_A(bc, 1); \
    G1_ST_B2(bs); \
    G1_BAR(); \
    __builtin_amdgcn_s_setprio(1); G1_MM(accG, 1, b1F); __builtin_amdgcn_s_setprio(0); \
    G1_BAR(); \
    /* phase 3: V, mh=1 */ \
    asm volatile("s_waitcnt vmcnt(2)" ::: "memory"); \
    G1_BAR(); \
    __builtin_amdgcn_s_setprio(1); G1_MM(accV, 1, b2F); __builtin_amdgcn_s_setprio(0); \
    G1_BAR(); \
    _Pragma("unroll") \
    for (int _i = 0; _i < 4; _i++) offA[_i] += 128; \
    _Pragma("unroll") \
    for (int _j = 0; _j < 2; _j++) offB[_j] += 128; \
} while (0)

__global__ __launch_bounds__(512, 2)
void gemm1_kernel(const unsigned short* __restrict__ xb, const unsigned short* __restrict__ w1t,
                  const unsigned short* __restrict__ w2t, const int* __restrict__ counts,
                  const int* __restrict__ row_token, unsigned short* __restrict__ hidden) {
    const int e = blockIdx.z;
    const int r0 = blockIdx.y * 256;
    if (r0 >= counts[e]) return;
    const int f0 = blockIdx.x * 128;

    extern __shared__ char smem[];   // 2 x { A 32KB | B1 16KB | B2 16KB } = 128KB

    const int t = threadIdx.x;
    const int lane = t & 63;
    const int wave = t >> 6;
    const int wm = wave >> 2;        // 0..1 : 128-row group
    const int wn = wave & 3;         // 0..3 : 32-f group

    // ---- staging: linear LDS dest (t*16); source chunk pre-swizzled: c = pos ^ (row&7)
    const int csrc = (((t & 7) ^ ((t >> 3) & 7)) << 4);
    const int srow = t >> 3;         // 0..63 within each 64-row staging round

    const char* xbc = (const char*)xb;
    const char* w1c = (const char*)w1t;
    const char* w2c = (const char*)w2t;
    char* ldsT = smem + t * 16;

    unsigned offA[4];
#pragma unroll
    for (int i = 0; i < 4; i++) {
        int tok = row_token[e * CAP + r0 + i * 64 + srow];
        offA[i] = (unsigned)tok * (DM * 2) + csrc;
    }
    unsigned offB[2];
#pragma unroll
    for (int j = 0; j < 2; j++)
        offB[j] = (unsigned)(e * DFF + f0 + j * 64 + srow) * (DM * 2) + csrc;

    // ---- ds_read addressing: row*128B + ((kk*4+lq)^ (row&7))*16; row&7 == l15&7
    const int l15 = lane & 15;
    const int lq = lane >> 4;
    const int swz = l15 & 7;
    const int cof0 = ((lq) ^ swz) << 4;
    const int cof1 = ((4 + lq) ^ swz) << 4;
    const int aRow = (wm * 128 + l15) * 128;
    const int bRow = (wn * 32 + l15) * 128;

    f32x4 accG[8][2], accV[8][2];
#pragma unroll
    for (int i = 0; i < 8; i++)
#pragma unroll
        for (int j = 0; j < 2; j++) {
            accG[i][j] = (f32x4){0.f, 0.f, 0.f, 0.f};
            accV[i][j] = (f32x4){0.f, 0.f, 0.f, 0.f};
        }

    bf16x8 aF[4][2], b1F[2][2], b2F[2][2];

    // ---- prologue: stage tile 0 into buf0, full drain once
    G1_ST_A(ldsT);
    G1_ST_B1(ldsT);
    G1_ST_B2(ldsT);
#pragma unroll
    for (int i = 0; i < 4; i++) offA[i] += 128;
#pragma unroll
    for (int j = 0; j < 2; j++) offB[j] += 128;
    asm volatile("s_waitcnt vmcnt(0)" ::: "memory");
    G1_BAR();

    // ---- main loop: 15 staging iterations (tiles 0..14), K = 16 tiles of 64
#pragma unroll 1
    for (int it = 0; it < 7; ++it) {
        G1_ITER(0, 1);
        G1_ITER(1, 0);
    }
    G1_ITER(0, 1);   // kt = 14, stages tile 15 into buf1

    // ---- epilogue tile 15 (buf1): drain remaining B2, then compute freely
    {
        const char* bc = smem + 65536;
        asm volatile("s_waitcnt vmcnt(0)" ::: "memory");
        G1_BAR();
        G1_RD_A(bc, 0);
        G1_RD_B(bc, 32768, b1F);
        G1_RD_B(bc, 49152, b2F);
        G1_MM(accG, 0, b1F);
        G1_MM(accV, 0, b2F);
        G1_RD_A(bc, 1);
        G1_MM(accG, 1, b1F);
        G1_MM(accV, 1, b2F);
    }

    // ---- silu(g)*v epilogue -> hidden bf16
    const size_t hbase = ((size_t)e * CAP + r0) * DFF + f0;
    const int mBase = wm * 128;
    const int nBase = wn * 32;
#pragma unroll
    for (int mf = 0; mf < 8; mf++)
#pragma unroll
        for (int ff = 0; ff < 2; ff++)
#pragma unroll
            for (int r = 0; r < 4; r++) {
                int m = mBase + mf * 16 + lq * 4 + r;
                int n = nBase + ff * 16 + l15;
                float g = accG[mf][ff][r];
                float v = accV[mf][ff][r];
                float h = (g / (1.f + __expf(-g))) * v;
                hidden[hbase + (size_t)m * DFF + n] = f2bf(h);
            }
}

// ---- GEMM2: out_rows[slot] = (hidden @ w3^T) * row_weight, bf16, no atomics ----
__global__ __launch_bounds__(256, 3)
void gemm2_kernel(const unsigned short* __restrict__ hidden, const unsigned short* __restrict__ w3t,
                  const int* __restrict__ counts, const float* __restrict__ row_weight,
                  unsigned short* __restrict__ out_rows) {
    const int e = blockIdx.z;
    const int r0 = blockIdx.y * 128;
    if (r0 >= counts[e]) return;
    const int d0 = blockIdx.x * 128;

    __shared__ unsigned short lA[128 * 32];
    __shared__ unsigned short lB[128 * 32];

    const int t = threadIdx.x;
    const int lane = t & 63;
    const int wave = t >> 6;

    const int rstage = t >> 2;
    const int cs = (t & 3) ^ ((rstage >> 1) & 3);
    const int kbyte = cs * 16;

    const char* pA0 = (const char*)(hidden + ((size_t)e * CAP + r0 + rstage) * DFF) + kbyte;
    const char* pA1 = pA0 + (size_t)64 * DFF * 2;
    const char* pB0 = (const char*)(w3t + ((size_t)e * DM + d0 + rstage) * DFF) + kbyte;
    const char* pB1 = pB0 + (size_t)64 * DFF * 2;

    char* lAp = (char*)lA + t * 16;
    char* lBp = (char*)lB + t * 16;

    const int mw = (wave & 1) * 64;
    const int nw = (wave >> 1) * 64;
    const int l15 = lane & 15;
    const int lq = lane >> 4;
    const int swz = (l15 >> 1) & 3;
    const unsigned short* aBase = lA + (mw + l15) * 32 + ((lq ^ swz) * 8);
    const unsigned short* bBase = lB + (nw + l15) * 32 + ((lq ^ swz) * 8);

    f32x4 acc[4][4];
#pragma unroll
    for (int i = 0; i < 4; i++)
#pragma unroll
        for (int j = 0; j < 4; j++) acc[i][j] = (f32x4){0.f, 0.f, 0.f, 0.f};

    for (int k0 = 0; k0 < DFF; k0 += 32) {
        glds16(pA0, lAp);  glds16(pA1, lAp + 4096);
        glds16(pB0, lBp);  glds16(pB1, lBp + 4096);
        pA0 += 64; pA1 += 64; pB0 += 64; pB1 += 64;
        __syncthreads();

        bf16x8 a[4], b[4];
#pragma unroll
        for (int i = 0; i < 4; i++) {
            a[i] = *(const bf16x8*)(aBase + i * 512);
            b[i] = *(const bf16x8*)(bBase + i * 512);
        }
#pragma unroll
        for (int i = 0; i < 4; i++)
#pragma unroll
            for (int j = 0; j < 4; j++)
                acc[i][j] = __builtin_amdgcn_mfma_f32_16x16x32_bf16(a[i], b[j], acc[i][j], 0, 0, 0);
        __syncthreads();
    }

    const float* rw = row_weight + e * CAP + r0;
#pragma unroll
    for (int i = 0; i < 4; i++)
#pragma unroll
        for (int r = 0; r < 4; r++) {
            int m = mw + i * 16 + lq * 4 + r;
            float w = rw[m];   // 0 for padding rows (memset) -> writes 0
            unsigned short* orow = out_rows + ((size_t)(e * CAP + r0 + m)) * DM + d0 + nw + l15;
#pragma unroll
            for (int j = 0; j < 4; j++)
                orow[j * 16] = f2bf(acc[i][j][r] * w);
        }
}

// ---- combine: out[tok] = out_rows[slot0] + out_rows[slot1] (pre-weighted) ----
__global__ void combine_kernel(const int* __restrict__ slot_of,
                               const unsigned short* __restrict__ out_rows,
                               float4* __restrict__ out) {
    const int tok = blockIdx.x;
    const int t = threadIdx.x;
    const int s0 = slot_of[2 * tok];
    const int s1 = slot_of[2 * tok + 1];
    float4 acc = {0.f, 0.f, 0.f, 0.f};
    if (s0 >= 0) {
        ushort4 r = ((const ushort4*)(out_rows + (size_t)s0 * DM))[t];
        acc.x += bf2f(r.x); acc.y += bf2f(r.y); acc.z += bf2f(r.z); acc.w += bf2f(r.w);
    }
    if (s1 >= 0) {
        ushort4 r = ((const ushort4*)(out_rows + (size_t)s1 * DM))[t];
        acc.x += bf2f(r.x); acc.y += bf2f(r.y); acc.z += bf2f(r.z); acc.w += bf2f(r.w);
    }
    out[(size_t)tok * (DM / 4) + t] = acc;
}

extern "C" void kernel_launch(void* const* d_in, const int* in_sizes, int n_in,
                              void* d_out, int out_size, void* d_ws, size_t ws_size,
                              hipStream_t stream) {
    const float* x = (const float*)d_in[0];
    const int* eidx = (const int*)d_in[1];
    const float* ewt = (const float*)d_in[2];
    const float* w1 = (const float*)d_in[3];
    const float* w2 = (const float*)d_in[4];
    const float* w3 = (const float*)d_in[5];
    float* out = (float*)d_out;

    char* ws = (char*)d_ws;
    size_t off = 0;
    auto alloc = [&](size_t b) { size_t o = off; off += (b + 255) & ~(size_t)255; return o; };
    int*   counts     = (int*)(ws + alloc(N_EXP * 4));
    int*   row_token  = (int*)(ws + alloc((size_t)N_EXP * CAP * 4));
    float* row_weight = (float*)(ws + alloc((size_t)N_EXP * CAP * 4));
    size_t hdr_end = off;  // memset range: counts + row_token + row_weight
    int*   slot_of    = (int*)(ws + alloc((size_t)N_TOK * TOPK * 4));  // fully written by dispatch
    unsigned short* xb  = (unsigned short*)(ws + alloc((size_t)N_TOK * DM * 2));
    unsigned short* w1t = (unsigned short*)(ws + alloc((size_t)N_EXP * DFF * DM * 2));
    unsigned short* w2t = (unsigned short*)(ws + alloc((size_t)N_EXP * DFF * DM * 2));
    unsigned short* w3t = (unsigned short*)(ws + alloc((size_t)N_EXP * DM * DFF * 2));
    unsigned short* hidden = (unsigned short*)(ws + alloc((size_t)N_EXP * CAP * DFF * 2));
    // out_rows (48 MB) aliases w1t+w2t (64 MB) — both dead after gemm1 completes.
    unsigned short* out_rows = w1t;
    (void)ws_size; (void)in_sizes; (void)n_in;

    static bool attr_done = false;
    if (!attr_done) {
        hipFuncSetAttribute((const void*)gemm1_kernel,
                            hipFuncAttributeMaxDynamicSharedMemorySize, 131072);
        attr_done = true;
    }

    hipMemsetAsync(ws, 0, hdr_end, stream);  // counts + row_token + row_weight

    cvt_x_kernel<<<(N_TOK * DM / 4) / 256, 256, 0, stream>>>((const float4*)x, (ushort4*)xb);
    transpose_cvt64_kernel<<<dim3(DFF / 64, DM / 64, 16), 256, 0, stream>>>(w1, w2, w1t, w2t, DM, DFF);
    transpose_cvt64_kernel<<<dim3(DM / 64, DFF / 64, 8), 256, 0, stream>>>(w3, w3, w3t, w3t, DFF, DM);
    dispatch_kernel<<<(N_TOK * TOPK) / 256, 256, 0, stream>>>(eidx, ewt, counts, row_token, row_weight, slot_of);

    gemm1_kernel<<<dim3(DFF / 128, CAP / 256, N_EXP), 512, 131072, stream>>>(xb, w1t, w2t, counts, row_token, hidden);
    gemm2_kernel<<<dim3(DM / 128, CAP / 128, N_EXP), 256, 0, stream>>>(hidden, w3t, counts, row_weight, out_rows);
    combine_kernel<<<N_TOK, 256, 0, stream>>>(slot_of, out_rows, (float4*)out);
}